// Round 18
// baseline (327.471 us; speedup 1.0000x reference)
//
#include <hip/hip_runtime.h>
#include <hip/hip_bf16.h>

#define B_ 16
#define I_ 256
#define O_ 256
#define T_ 512
#define L_ 8192
#define K_ 7
#define PAD_ 3
#define BN 32
#define NTILE 256
#define LDK 264   // Xs row stride in bf16 elements (256 + 8 pad)
#define XFS 39    // Xf row stride in floats (odd -> conv reads spread all 32 banks)
#define XFN 2560  // 10*256 staged floats per chunk (64*39=2496 + tail pad)

typedef unsigned short u16;
typedef unsigned int u32;
typedef __attribute__((ext_vector_type(8))) short short8;
typedef __attribute__((ext_vector_type(4))) float f32x4;

__device__ inline u16 f2bf(float f) {
    union { float f; u32 u; } v; v.f = f;
    u32 r = v.u + 0x7FFF + ((v.u >> 16) & 1);   // RNE
    return (u16)(r >> 16);
}

// ---------------- Kernel 1: mod[b][i] = t[b,:] . mod_w[i,:] + mod_b[i] ----------------
__global__ void mod_kernel(const float* __restrict__ t, const float* __restrict__ mod_w,
                           const float* __restrict__ mod_b, float* __restrict__ mod) {
    int g = blockIdx.x, b = blockIdx.y;
    int lane = threadIdx.x & 63, wv = threadIdx.x >> 6;
    const float* tb = t + b * T_;
    #pragma unroll
    for (int q = 0; q < 4; ++q) {
        int i = g * 16 + wv * 4 + q;
        const float* wr = mod_w + (size_t)i * T_;
        float s = 0.f;
        #pragma unroll
        for (int u = 0; u < 8; ++u) s += wr[lane + u * 64] * tb[lane + u * 64];
        #pragma unroll
        for (int d = 32; d; d >>= 1) s += __shfl_down(s, d);
        if (lane == 0) mod[b * I_ + i] = s + mod_b[i];
    }
}

// ---------------- Kernel 2: Wb[b][o][i] = bf16( proj_w[o,i]*(mod[b,i]+1) * demod[b,o] ) ----
__global__ void wmod_kernel(const float* __restrict__ proj_w, const float* __restrict__ mod,
                            u16* __restrict__ Wb) {
    int og = blockIdx.x, b = blockIdx.y;
    int lane = threadIdx.x & 63, wv = threadIdx.x >> 6;
    const float* mrow = mod + b * I_;
    #pragma unroll
    for (int q = 0; q < 4; ++q) {
        int o = og * 16 + wv * 4 + q;
        const float* pw = proj_w + (size_t)o * I_;
        float4 pv = *(const float4*)(pw + lane * 4);
        float4 mv = *(const float4*)(mrow + lane * 4);
        float v0 = pv.x * (mv.x + 1.f);
        float v1 = pv.y * (mv.y + 1.f);
        float v2 = pv.z * (mv.z + 1.f);
        float v3 = pv.w * (mv.w + 1.f);
        float ss = v0*v0 + v1*v1 + v2*v2 + v3*v3;
        #pragma unroll
        for (int d = 32; d; d >>= 1) ss += __shfl_xor(ss, d);
        float dem = rsqrtf(ss + 1e-8f);
        u32 lo = (u32)f2bf(v0 * dem) | ((u32)f2bf(v1 * dem) << 16);
        u32 hi = (u32)f2bf(v2 * dem) | ((u32)f2bf(v3 * dem) << 16);
        *(uint2*)(Wb + (size_t)(b * O_ + o) * I_ + lane * 4) = make_uint2(lo, hi);
    }
}

// stage one 64-channel chunk: Xf-flat[f] = bx[ci0 + f/39][clamp(l0-4 + f%39)], f = k*256+tid
#define STAGE(CI0, DST) do { \
    int ch = ch_init, col = col_init; \
    _Pragma("unroll") \
    for (int k = 0; k < 10; ++k) { \
        int chc = ch < 63 ? ch : 63; \
        int p = l0 - 4 + col; \
        p = p < 0 ? 0 : (p > L_ - 1 ? L_ - 1 : p); \
        const float* gp = bxr + (size_t)((CI0) + chc) * L_ + p; \
        __builtin_amdgcn_global_load_lds( \
            (const __attribute__((address_space(1))) u32*)gp, \
            (__attribute__((address_space(3))) u32*)&(DST)[k * 256 + tid], 4, 0, 0); \
        ch += 6; col += 22; \
        if (col >= XFS) { col -= XFS; ch += 1; } \
    } } while (0)

// ---------------- Kernel 3: fused conv + GEMM, pipelined DMA (T3/T4 2-phase) ----------------
// R17 post-mortem: occupancy 50% changed nothing -> co-resident blocks phase-lock and the
// fetch pipe idles during compute/store phases; every __syncthreads() also drains vmcnt(0).
// Fix: double-buffered Xf; issue chunk ck+1's 10 DMA loads BEFORE computing chunk ck;
// counted s_waitcnt vmcnt(10) + raw s_barrier keeps them in flight ACROSS the barrier
// (AITER/T4 pattern). Conv weights preloaded + vmcnt(0) so no other VMEM pollutes the
// count (in-order vmcnt retirement). Edge padding now zeroed in-register (no fix phase).
__global__ __launch_bounds__(256, 4) void main_kernel(
    const float* __restrict__ bx, const float* __restrict__ conv_w,
    const u16* __restrict__ Wb, const float* __restrict__ proj_b,
    float* __restrict__ out)
{
    __shared__ __align__(16) float Xf[2][XFN];    // 20,480 B (double-buffered chunks)
    __shared__ __align__(16) u16 Xs[BN * LDK];    // 16,896 B -> total 37.4 KB, 4 blocks/CU

    const int tile = blockIdx.x;
    const int b = blockIdx.y;
    const int l0 = tile * BN;
    const int tid = threadIdx.x;
    const int lane = tid & 63;
    const int wv = tid >> 6;
    const int mlane = lane & 15;
    const int quad = lane >> 4;
    const float* bxr = bx + (size_t)b * I_ * L_;

    const int ch_init = tid / XFS;
    const int col_init = tid - ch_init * XFS;
    const int chl = tid & 63;                  // conv channel within chunk
    const int s8v = (tid >> 6) << 3;           // conv l-offset 0,8,16,24 (wave-uniform)

    // preload conv weights for this thread's 4 channels (one per chunk); drain so the
    // pipeline's vmcnt counting sees only the DMA loads.
    float wAll[4][K_];
    #pragma unroll
    for (int ck = 0; ck < 4; ++ck)
        #pragma unroll
        for (int j = 0; j < K_; ++j)
            wAll[ck][j] = conv_w[((ck << 6) + chl) * K_ + j];
    asm volatile("s_waitcnt vmcnt(0)" ::: "memory");

    STAGE(0, Xf[0]);   // prologue: chunk 0 in flight (10 DMA per wave)

    #pragma unroll
    for (int ck = 0; ck < 4; ++ck) {
        if (ck < 3) {
            STAGE((ck + 1) << 6, Xf[(ck + 1) & 1]);      // chunk ck+1 in flight
            asm volatile("s_waitcnt vmcnt(10)" ::: "memory");  // chunk ck landed; ck+1 stays out
        } else {
            asm volatile("s_waitcnt vmcnt(0)" ::: "memory");
        }
        __builtin_amdgcn_sched_barrier(0);
        __builtin_amdgcn_s_barrier();                    // all waves: chunk ck data visible
        __builtin_amdgcn_sched_barrier(0);

        // ---- conv chunk ck from Xf[ck&1] (stride-39 rows: conflict-free b32 reads) ----
        {
            const int ci0 = ck << 6;
            const float* xr = &Xf[ck & 1][chl * XFS];
            float x[14];
            #pragma unroll
            for (int m = 0; m < 14; ++m) x[m] = xr[s8v + 1 + m];   // cols s8v+1 .. s8v+14
            // 'same'-padding semantics, in-register (staged data is clamped garbage there)
            if (tile == 0 && s8v == 0)          { x[0] = 0.f; x[1] = 0.f; x[2] = 0.f; }
            if (tile == NTILE - 1 && s8v == 24) { x[11] = 0.f; x[12] = 0.f; x[13] = 0.f; }
            #pragma unroll
            for (int n = 0; n < 8; ++n) {                // output l = l0 + s8v + n
                float s = 0.f;
                #pragma unroll
                for (int j = 0; j < K_; ++j) s += wAll[ck][j] * x[n + j];
                Xs[(s8v + n) * LDK + (ci0 + chl)] = f2bf(s);
            }
        }
        asm volatile("s_waitcnt lgkmcnt(0)" ::: "memory");  // our Xs writes visible
        __builtin_amdgcn_sched_barrier(0);
        __builtin_amdgcn_s_barrier();                    // conv(ck) done: buffer reusable
        __builtin_amdgcn_sched_barrier(0);
    }

    // ---- Phase 2: GEMM (BN=32: 4 m-frags x 2 n-frags per wave) ----
    f32x4 acc[4][2];
    #pragma unroll
    for (int r = 0; r < 4; ++r)
        #pragma unroll
        for (int c = 0; c < 2; ++c)
            acc[r][c] = (f32x4){0.f, 0.f, 0.f, 0.f};

    const u16* Wrow = Wb + (size_t)(b * O_ + wv * 64 + mlane) * I_;

    for (int kb = 0; kb < 8; ++kb) {
        const int koff = kb * 32 + quad * 8;
        short8 a[4], bbf[2];
        #pragma unroll
        for (int r = 0; r < 4; ++r)
            a[r] = *(const short8*)(Wrow + r * 16 * I_ + koff);
        #pragma unroll
        for (int c = 0; c < 2; ++c)
            bbf[c] = *(const short8*)(&Xs[(c * 16 + mlane) * LDK + koff]);
        #pragma unroll
        for (int r = 0; r < 4; ++r)
            #pragma unroll
            for (int c = 0; c < 2; ++c)
                acc[r][c] = __builtin_amdgcn_mfma_f32_16x16x32_bf16(a[r], bbf[c], acc[r][c], 0, 0, 0);
    }

    // ---- Epilogue: + proj_b, store ----
    float* outb = out + (size_t)b * O_ * L_;
    #pragma unroll
    for (int r = 0; r < 4; ++r) {
        const int obase = wv * 64 + r * 16 + quad * 4;
        #pragma unroll
        for (int p = 0; p < 4; ++p) {
            const int o = obase + p;
            const float bias = proj_b[o];
            float* orow = outb + (size_t)o * L_ + l0 + mlane;
            #pragma unroll
            for (int c = 0; c < 2; ++c)
                orow[c * 16] = acc[r][c][p] + bias;
        }
    }
}

extern "C" void kernel_launch(void* const* d_in, const int* in_sizes, int n_in,
                              void* d_out, int out_size, void* d_ws, size_t ws_size,
                              hipStream_t stream) {
    const float* bx     = (const float*)d_in[0];
    const float* t      = (const float*)d_in[1];
    const float* conv_w = (const float*)d_in[2];
    const float* proj_w = (const float*)d_in[3];
    const float* proj_b = (const float*)d_in[4];
    const float* mod_w  = (const float*)d_in[5];
    const float* mod_b  = (const float*)d_in[6];
    float* out = (float*)d_out;

    float* mod = (float*)d_ws;                       // 16 KB
    u16*   Wb  = (u16*)((char*)d_ws + 16384);        // 2 MB bf16 modulated weights

    mod_kernel<<<dim3(16, 16), 256, 0, stream>>>(t, mod_w, mod_b, mod);
    wmod_kernel<<<dim3(16, 16), 256, 0, stream>>>(proj_w, mod, Wb);
    main_kernel<<<dim3(NTILE, 16), 256, 0, stream>>>(bx, conv_w, Wb, proj_b, out);
}

// Round 20
// 271.451 us; speedup vs baseline: 1.2064x; 1.2064x over previous
//
#include <hip/hip_runtime.h>
#include <hip/hip_bf16.h>

#define B_ 16
#define I_ 256
#define O_ 256
#define T_ 512
#define L_ 8192
#define K_ 7
#define PAD_ 3
#define BN 64
#define NT 8        // consecutive tiles per persistent block
#define GROUPS 16   // GROUPS*NT = 128 tiles
#define LDK 264     // Xs row stride in bf16 (256 + 8 pad)
#define XFS 71      // Xf row stride in floats (64 + 7 halo; odd -> bank-spread)
#define XFN 18432   // 36*512 (256*71=18176 + tail pad)

typedef unsigned short u16;
typedef unsigned int u32;
typedef __attribute__((ext_vector_type(8))) short short8;
typedef __attribute__((ext_vector_type(4))) float f32x4;

__device__ inline u16 f2bf(float f) {
    union { float f; u32 u; } v; v.f = f;
    u32 r = v.u + 0x7FFF + ((v.u >> 16) & 1);   // RNE
    return (u16)(r >> 16);
}

// ---------------- Kernel 1: mod[b][i] = t[b,:] . mod_w[i,:] + mod_b[i] ----------------
__global__ void mod_kernel(const float* __restrict__ t, const float* __restrict__ mod_w,
                           const float* __restrict__ mod_b, float* __restrict__ mod) {
    int g = blockIdx.x, b = blockIdx.y;
    int lane = threadIdx.x & 63, wv = threadIdx.x >> 6;
    const float* tb = t + b * T_;
    #pragma unroll
    for (int q = 0; q < 4; ++q) {
        int i = g * 16 + wv * 4 + q;
        const float* wr = mod_w + (size_t)i * T_;
        float s = 0.f;
        #pragma unroll
        for (int u = 0; u < 8; ++u) s += wr[lane + u * 64] * tb[lane + u * 64];
        #pragma unroll
        for (int d = 32; d; d >>= 1) s += __shfl_down(s, d);
        if (lane == 0) mod[b * I_ + i] = s + mod_b[i];
    }
}

// ---------------- Kernel 2: Wb[b][o][i] = bf16( proj_w[o,i]*(mod[b,i]+1) * demod[b,o] ) ----
__global__ void wmod_kernel(const float* __restrict__ proj_w, const float* __restrict__ mod,
                            u16* __restrict__ Wb) {
    int og = blockIdx.x, b = blockIdx.y;
    int lane = threadIdx.x & 63, wv = threadIdx.x >> 6;
    const float* mrow = mod + b * I_;
    #pragma unroll
    for (int q = 0; q < 4; ++q) {
        int o = og * 16 + wv * 4 + q;
        const float* pw = proj_w + (size_t)o * I_;
        float4 pv = *(const float4*)(pw + lane * 4);
        float4 mv = *(const float4*)(mrow + lane * 4);
        float v0 = pv.x * (mv.x + 1.f);
        float v1 = pv.y * (mv.y + 1.f);
        float v2 = pv.z * (mv.z + 1.f);
        float v3 = pv.w * (mv.w + 1.f);
        float ss = v0*v0 + v1*v1 + v2*v2 + v3*v3;
        #pragma unroll
        for (int d = 32; d; d >>= 1) ss += __shfl_xor(ss, d);
        float dem = rsqrtf(ss + 1e-8f);
        u32 lo = (u32)f2bf(v0 * dem) | ((u32)f2bf(v1 * dem) << 16);
        u32 hi = (u32)f2bf(v2 * dem) | ((u32)f2bf(v3 * dem) << 16);
        *(uint2*)(Wb + (size_t)(b * O_ + o) * I_ + lane * 4) = make_uint2(lo, hi);
    }
}

// stage one full tile: Xf-flat[f] = bx[f/71][clamp(l0t-4 + f%71)], f = k*512 + tid
#define STAGE(L0T) do { \
    int ch = ch0, col = col0; \
    _Pragma("unroll") \
    for (int k = 0; k < 36; ++k) { \
        int chc = ch < 255 ? ch : 255; \
        int p = (L0T) - 4 + col; \
        p = p < 0 ? 0 : (p > L_ - 1 ? L_ - 1 : p); \
        const float* gp = bxr + (size_t)chc * L_ + p; \
        __builtin_amdgcn_global_load_lds( \
            (const __attribute__((address_space(1))) u32*)gp, \
            (__attribute__((address_space(3))) u32*)&Xf[k * 512 + tid], 4, 0, 0); \
        ch += 7; col += 15; \
        if (col >= XFS) { col -= XFS; ch += 1; } \
    } } while (0)

// ------- Kernel 3: persistent cross-tile-pipelined fused conv + GEMM (1 block/CU) -------
// R18 post-mortem: counted-vmcnt overlap worked (+BW) but spilled (VGPR 64, +73MB scratch
// traffic); and intra-chunk pipelining can't help because conv is tiny vs fetch. Real fix:
// hide tile t+1's FETCH under tile t's GEMM+STORE. Persistent block, NT=8 tiles:
//   barrier(stage t landed) -> conv(t) -> barrier -> ISSUE stage(t+1) -> GEMM -> store.
// A-frags + biases are tile-invariant: preloaded to regs ONCE (64 VGPR) -> in-loop VMEM is
// stage DMA + stores only; GEMM gated on lgkm only, so stage stays in flight through it.
// __launch_bounds__(512,2) = 256-VGPR cap: no spills. b = id&15 clusters same-b on XCDs.
__global__ __launch_bounds__(512, 2) void main_kernel(
    const float* __restrict__ bx, const float* __restrict__ conv_w,
    const u16* __restrict__ Wb, const float* __restrict__ proj_b,
    float* __restrict__ out)
{
    __shared__ __align__(16) float Xf[XFN];       // 73,728 B
    __shared__ __align__(16) u16 Xs[BN * LDK];    // 33,792 B  -> 107.5 KB, 1 block/CU

    const int id = blockIdx.x;
    const int b = id & 15;
    const int group = id >> 4;
    const int tid = threadIdx.x;
    const int lane = tid & 63;
    const int wv = tid >> 6;                       // 0..7
    const int mlane = lane & 15;
    const int quad = lane >> 4;
    const float* bxr = bx + (size_t)b * I_ * L_;
    float* outb = out + (size_t)b * O_ * L_;

    const int cch = tid & 255;                     // conv channel
    const int half = tid >> 8;                     // conv l-half (0/1)
    const int ch0 = tid / XFS;                     // stage walk init
    const int col0 = tid - ch0 * XFS;

    // ---- tile-invariant preloads (drained at first barrier) ----
    float w[K_];
    #pragma unroll
    for (int j = 0; j < K_; ++j) w[j] = conv_w[cch * K_ + j];

    short8 aF[2][8];                               // this wave's A-frags: 32 o-rows x 256 k
    const u16* Wrow = Wb + (size_t)(b * O_ + wv * 32 + mlane) * I_;
    #pragma unroll
    for (int r = 0; r < 2; ++r)
        #pragma unroll
        for (int kb = 0; kb < 8; ++kb)
            aF[r][kb] = *(const short8*)(Wrow + r * 16 * I_ + kb * 32 + quad * 8);

    float bias[2][4];
    #pragma unroll
    for (int r = 0; r < 2; ++r)
        #pragma unroll
        for (int p = 0; p < 4; ++p)
            bias[r][p] = proj_b[wv * 32 + r * 16 + quad * 4 + p];

    STAGE(group * NT * BN);                        // tile 0 of this block in flight

    for (int t = 0; t < NT; ++t) {
        const int tile = group * NT + t;
        const int l0 = tile * BN;
        __syncthreads();                           // stage(t) landed (full drain)

        // ---- conv tile t: Xf -> Xs (LDS only; stride-71 rows bank-spread) ----
        {
            const float* xr = &Xf[cch * XFS + half * 32];
            float x[38];
            #pragma unroll
            for (int m = 0; m < 38; ++m) x[m] = xr[1 + m];   // col half*32+1+m
            if (tile == 0 && half == 0)       { x[0] = 0.f; x[1] = 0.f; x[2] = 0.f; }
            if (tile == 127 && half == 1)     { x[35] = 0.f; x[36] = 0.f; x[37] = 0.f; }
            #pragma unroll
            for (int n = 0; n < 32; ++n) {                   // out l = l0 + half*32 + n
                float s = 0.f;
                #pragma unroll
                for (int j = 0; j < K_; ++j) s += w[j] * x[n + j];
                Xs[(half * 32 + n) * LDK + cch] = f2bf(s);
            }
        }
        __syncthreads();                           // Xs ready; Xf free for next stage

        if (t + 1 < NT) STAGE(l0 + BN);            // tile t+1 fetch in flight through GEMM+store

        // ---- GEMM tile t: regs(A) x LDS(B) -> acc (no VMEM waits) ----
        f32x4 acc[2][4];
        #pragma unroll
        for (int r = 0; r < 2; ++r)
            #pragma unroll
            for (int c = 0; c < 4; ++c)
                acc[r][c] = (f32x4){0.f, 0.f, 0.f, 0.f};

        #pragma unroll
        for (int kb = 0; kb < 8; ++kb) {
            const int koff = kb * 32 + quad * 8;
            short8 bbf[4];
            #pragma unroll
            for (int c = 0; c < 4; ++c)
                bbf[c] = *(const short8*)(&Xs[(c * 16 + mlane) * LDK + koff]);
            #pragma unroll
            for (int r = 0; r < 2; ++r)
                #pragma unroll
                for (int c = 0; c < 4; ++c)
                    acc[r][c] = __builtin_amdgcn_mfma_f32_16x16x32_bf16(aF[r][kb], bbf[c], acc[r][c], 0, 0, 0);
        }

        // ---- store tile t (concurrent with stage(t+1) reads) ----
        #pragma unroll
        for (int r = 0; r < 2; ++r) {
            const int obase = wv * 32 + r * 16 + quad * 4;
            #pragma unroll
            for (int p = 0; p < 4; ++p) {
                float* orow = outb + (size_t)(obase + p) * L_ + l0 + mlane;
                #pragma unroll
                for (int c = 0; c < 4; ++c)
                    orow[c * 16] = acc[r][c][p] + bias[r][p];
            }
        }
    }
}

extern "C" void kernel_launch(void* const* d_in, const int* in_sizes, int n_in,
                              void* d_out, int out_size, void* d_ws, size_t ws_size,
                              hipStream_t stream) {
    const float* bx     = (const float*)d_in[0];
    const float* t      = (const float*)d_in[1];
    const float* conv_w = (const float*)d_in[2];
    const float* proj_w = (const float*)d_in[3];
    const float* proj_b = (const float*)d_in[4];
    const float* mod_w  = (const float*)d_in[5];
    const float* mod_b  = (const float*)d_in[6];
    float* out = (float*)d_out;

    float* mod = (float*)d_ws;                       // 16 KB
    u16*   Wb  = (u16*)((char*)d_ws + 16384);        // 2 MB bf16 modulated weights

    mod_kernel<<<dim3(16, 16), 256, 0, stream>>>(t, mod_w, mod_b, mod);
    wmod_kernel<<<dim3(16, 16), 256, 0, stream>>>(proj_w, mod, Wb);
    main_kernel<<<dim3(GROUPS * 16), 512, 0, stream>>>(bx, conv_w, Wb, proj_b, out);
}